// Round 11
// baseline (4340.667 us; speedup 1.0000x reference)
//
#include <hip/hip_runtime.h>

#define BDIM 64
#define TDIM 1024
#define DDIM 256
#define HDIM 512
#define RING 8

typedef unsigned short ushort_t;
typedef unsigned int uint32;
typedef unsigned long long ull;
typedef __attribute__((ext_vector_type(8))) short short8;
typedef __attribute__((ext_vector_type(4))) float f32x4;

__device__ __forceinline__ ushort_t f2bf(float f) {
  union { float f; uint32 u; } v; v.f = f;
  uint32 u = v.u;
  return (ushort_t)((u + 0x7fffu + ((u >> 16) & 1u)) >> 16);
}

__device__ __forceinline__ short8 pack8(float4 a, float4 b) {
  short8 s;
  s[0] = (short)f2bf(a.x); s[1] = (short)f2bf(a.y);
  s[2] = (short)f2bf(a.z); s[3] = (short)f2bf(a.w);
  s[4] = (short)f2bf(b.x); s[5] = (short)f2bf(b.y);
  s[6] = (short)f2bf(b.z); s[7] = (short)f2bf(b.w);
  return s;
}

__device__ __forceinline__ uint32 ld_sc1(uint32* p) {
  return __hip_atomic_load(p, __ATOMIC_RELAXED, __HIP_MEMORY_SCOPE_AGENT);
}
__device__ __forceinline__ void st_sc1(uint32* p, uint32 v) {
  __hip_atomic_store(p, v, __ATOMIC_RELAXED, __HIP_MEMORY_SCOPE_AGENT);
}
__device__ __forceinline__ void st_sc1_u64(ull* p, ull v) {
  __hip_atomic_store(p, v, __ATOMIC_RELAXED, __HIP_MEMORY_SCOPE_AGENT);
}
__device__ __forceinline__ ull ld_sc1_u64(const ull* p) {
  return __hip_atomic_load((ull*)p, __ATOMIC_RELAXED, __HIP_MEMORY_SCOPE_AGENT);
}

// 16-word sc1 poll: lanes 0..15 each watch one flag; wave-wide __all join.
__device__ __forceinline__ void poll16(uint32* base, uint32 tgt, int lane, int cap) {
  int it = 0;
  for (;;) {
    uint32 v = ld_sc1(base + (lane & 15));
    if (__all((int)(v >= tgt))) break;
    __builtin_amdgcn_s_sleep(1);
    if (++it > cap) break;   // bounded: wrong beats hang
  }
  asm volatile("" ::: "memory");
}

// ---- fragment-major LDS layout (conflict-free MFMA reads, r10-proven) ----
// chunk(row,lg;kf) = (lg*16+row) ^ (kf&7); chunk holds A[row][kf*32+lg*8 .. +8]
__device__ __forceinline__ int frag_off(int row, int kf, int lg) {   // ushort units
  return kf * 512 + (((lg * 16 + row) ^ (kf & 7)) << 3);
}

// 512-thread staging of a 16x512 bf16 tile (2048 ull, row-major src) -> fragment-major
__device__ __forceinline__ void ds_stage512(ushort_t* dst, int tid, const ull* v) {
#pragma unroll
  for (int q = 0; q < 4; ++q) {
    int idx = q * 512 + tid;
    int row = idx >> 7, inner = idx & 127;
    int kf = inner >> 3, lg = (inner >> 1) & 3, e = (inner & 1) * 4;
    *(ull*)&dst[frag_off(row, kf, lg) + e] = v[q];
  }
}
__device__ __forceinline__ void load4_sc1(const ull* src, int tid, ull* v) {
#pragma unroll
  for (int q = 0; q < 4; ++q) v[q] = ld_sc1_u64(src + q * 512 + tid);
}

__global__ void __launch_bounds__(512, 1)
lstm_fused(const float* __restrict__ x,
           const float* __restrict__ w_ih0, const float* __restrict__ w_hh0,
           const float* __restrict__ b0,
           const float* __restrict__ w_ih1, const float* __restrict__ w_hh1,
           const float* __restrict__ b1,
           float* __restrict__ out,
           uint32* h0F, uint32* h1F, uint32* consF,
           ushort_t* ring, ushort_t* h0buf, ushort_t* h1buf)
{
  const int b     = (int)blockIdx.x;      // 0..127
  const int g     = b & 7;
  const int layer = g >> 2;
  const int bt    = g & 3;
  const int ct    = b >> 3;               // 0..15 (32 h-cols each)
  const int tid   = (int)threadIdx.x;
  const int wv    = tid >> 6;             // 0..7
  const int lane  = tid & 63;
  const int n     = lane & 15;            // B/C column within wave tile
  const int rg    = lane >> 4;            // C row group
  const int gsel  = n >> 2;               // gate: 0=i 1=f 2=o 3=g
  const int cgl   = n & 3;                // h-col within wave's 4

  __shared__ __align__(16) ushort_t Is[16 * 512];   // fragment-major input tile
  __shared__ __align__(16) ushort_t Hs[16 * 512];   // fragment-major h tile
  __shared__ __align__(16) ushort_t htmp[8][16][4]; // per-wave 4x4 transpose slab
  __shared__ float htmpf[2][16][32];                // layer1 deferred out

  const int NI  = layer ? 16 : 8;
  const int Din = layer ? HDIM : DDIM;
  const float* wih = layer ? w_ih1 : w_ih0;
  const float* whh = layer ? w_hh1 : w_hh0;
  const float* bb  = layer ? b1 : b0;
  const int grow = gsel * HDIM + ct * 32 + wv * 4 + cgl;

  short8 wf[32];
#pragma unroll
  for (int kf = 0; kf < 32; ++kf) wf[kf] = (short8)((short)0);
#pragma unroll
  for (int kf = 0; kf < 32; ++kf) {
    if (kf < NI + 16) {
      const float* src;
      if (kf < NI) src = wih + (size_t)grow * Din + (size_t)kf * 32 + rg * 8;
      else         src = whh + (size_t)grow * HDIM + (size_t)(kf - NI) * 32 + rg * 8;
      float4 a = *(const float4*)(src);
      float4 bq = *(const float4*)(src + 4);
      wf[kf] = pack8(a, bq);
    }
  }
  const float bias = bb[grow];
  const bool isg = (gsel == 3);

  const ull* ring_u = (const ull*)ring;                       // [4bt][8][2048]
  ull* hbuf_u = (ull*)(layer ? h1buf : h0buf) + (size_t)bt * 4096;  // [2][2048]
  uint32* hF   = (layer ? h1F : h0F) + bt * 16;               // [16]
  uint32* rF   = h0F + bt * 16;                               // ring flags = layer0 hF
  uint32* cnsF = consF + bt * 16;                             // [16]

  // x staging map (layer0): thread -> row (tid>>5), colblk (tid&31) = one chunk
  const int xrow = tid >> 5, xcb = tid & 31;

  float4 xpa, xpb;     // layer0: x[t] regs
  ull rvA[4];          // layer1: ring[t] regs
  if (layer == 0) {
    const float4* xv = (const float4*)(x + (size_t)(bt * 16 + xrow) * (TDIM * DDIM) + xcb * 8);
    xpa = xv[0]; xpb = xv[1];
  } else {
    poll16(rF, 1u, lane, 4000000);                 // ring[0] ready
    ull rv0[4];
    load4_sc1(ring_u + (size_t)bt * 16384, tid, rv0);
    ds_stage512(Is, tid, rv0);
  }

  float c4[4] = {0.f, 0.f, 0.f, 0.f};   // valid on n<4 lanes

  for (int t = 0; t < TDIM; ++t) {
    // ---- P1: polls (all waves redundantly) ----
    if (t > 0) poll16(hF, (uint32)t, lane, 200000);
    if (layer == 0 && t >= RING) poll16(cnsF, (uint32)(t - RING + 1), lane, 200000);
    // ---- P2: h[t-1] chain load ----
    ull hv[4];
    if (t > 0) load4_sc1(hbuf_u + (size_t)((t - 1) & 1) * 2048, tid, hv);
    // ---- P3: stage ----
    if (t > 0) ds_stage512(Hs, tid, hv);
    if (layer == 0) {
      *(short8*)&Is[frag_off(xrow, xcb >> 2, xcb & 3)] = pack8(xpa, xpb);
    } else if (t > 0) {
      ds_stage512(Is, tid, rvA);       // ring[t], prefetched at P8 of t-1
    }
    __syncthreads();   // B1
    // ---- post-B1: ring credit + deferred coalesced out[t-1] ----
    if (layer == 1) {
      if (tid == 0) st_sc1(cnsF + ct, (uint32)(t + 1));   // slots <= t consumed
      if (t > 0) {
        float v = htmpf[(t - 1) & 1][tid >> 5][tid & 31];
        out[(size_t)(bt * 16 + (tid >> 5)) * (TDIM * HDIM)
            + (size_t)(t - 1) * HDIM + ct * 32 + (tid & 31)] = v;
      }
    }
    // ---- P5: MFMA ----
    f32x4 acc0 = {0.f, 0.f, 0.f, 0.f}, acc1 = {0.f, 0.f, 0.f, 0.f};
#pragma unroll
    for (int kf = 0; kf < 16; ++kf) {
      if (kf < NI) {
        const short8 af = *(const short8*)&Is[frag_off(n, kf, rg)];
        if (kf & 1) acc1 = __builtin_amdgcn_mfma_f32_16x16x32_bf16(af, wf[kf], acc1, 0, 0, 0);
        else        acc0 = __builtin_amdgcn_mfma_f32_16x16x32_bf16(af, wf[kf], acc0, 0, 0, 0);
      }
    }
    if (t > 0) {
#pragma unroll
      for (int kf = 0; kf < 16; ++kf) {
        const short8 af = *(const short8*)&Hs[frag_off(n, kf, rg)];
        if (kf & 1) acc1 = __builtin_amdgcn_mfma_f32_16x16x32_bf16(af, wf[NI + kf], acc1, 0, 0, 0);
        else        acc0 = __builtin_amdgcn_mfma_f32_16x16x32_bf16(af, wf[NI + kf], acc0, 0, 0, 0);
      }
    }
    // ---- P6: activation + shfl gate exchange + pointwise (all waves) ----
    float nh4[4], nc4[4];
#pragma unroll
    for (int i = 0; i < 4; ++i) {
      float v = acc0[i] + acc1[i] + bias;
      float e = __expf(isg ? 2.f * v : -v);
      float inv = 1.f / (1.f + e);
      float act = isg ? (1.f - 2.f * inv) : inv;   // tanh for g, sigmoid else
      float fo  = __shfl_xor(act, 4, 64);
      float oo  = __shfl_xor(act, 8, 64);
      float go_ = __shfl_xor(act, 12, 64);
      float nc = fo * c4[i] + act * go_;           // valid on gsel==0 lanes
      float e2 = __expf(2.f * nc);
      float th = 1.f - 2.f / (e2 + 1.f);
      float nh = oo * th;                          // h uses UNCLIPPED c
      nc = fminf(fmaxf(nc, -50.f), 50.f);
      nh = fminf(fmaxf(nh, -50.f), 50.f);
      c4[i] = nc; nh4[i] = nh; nc4[i] = nc;
    }
    // ---- P7: publish ----
    const int row2 = rg * 4 + cgl;
    if (n < 4) {
#pragma unroll
      for (int i = 0; i < 4; ++i) htmp[wv][rg * 4 + i][cgl] = f2bf(nh4[i]);
      if (layer == 1) {
#pragma unroll
        for (int i = 0; i < 4; ++i) htmpf[t & 1][rg * 4 + i][wv * 4 + cgl] = nh4[i];
      }
      asm volatile("s_waitcnt lgkmcnt(0)" ::: "memory");
      __builtin_amdgcn_sched_barrier(0);
      ull hrow = *(const ull*)&htmp[wv][row2][0];   // row row2, wave's 4 cols
      st_sc1_u64(hbuf_u + (size_t)(t & 1) * 2048 + row2 * 128 + ct * 8 + wv, hrow);
      if (layer == 0)
        st_sc1_u64((ull*)ring_u + (size_t)bt * 16384 + (size_t)(t & 7) * 2048
                   + row2 * 128 + ct * 8 + wv, hrow);
      if (t == TDIM - 1) {
        const size_t OH = (size_t)BDIM * TDIM * HDIM;
        const size_t OC = OH + 2 * (size_t)BDIM * HDIM;
        const int hc = ct * 32 + wv * 4 + cgl;
#pragma unroll
        for (int i = 0; i < 4; ++i) {
          out[OH + (size_t)layer * BDIM * HDIM + (size_t)(bt * 16 + rg * 4 + i) * HDIM + hc] = nh4[i];
          out[OC + (size_t)layer * BDIM * HDIM + (size_t)(bt * 16 + rg * 4 + i) * HDIM + hc] = nc4[i];
        }
      }
    }
    asm volatile("s_waitcnt vmcnt(0)" ::: "memory");   // per-wave: h+ring+out acked
    __syncthreads();   // B2: whole block certified
    if (tid == 0) st_sc1(hF + ct, (uint32)(t + 1));    // certifies h[t] (+ring[t])
    // ---- P8: shadow prefetch for t+1 ----
    if (layer == 0) {
      if (t + 1 < TDIM) {
        const float4* xv = (const float4*)(x + (size_t)(bt * 16 + xrow) * (TDIM * DDIM)
                                             + (size_t)(t + 1) * DDIM + xcb * 8);
        xpa = xv[0]; xpb = xv[1];
      }
    } else if (t + 1 < TDIM) {
      poll16(rF, (uint32)(t + 2), lane, 200000);       // ring[t+1] certified
      load4_sc1(ring_u + (size_t)bt * 16384 + (size_t)((t + 1) & 7) * 2048, tid, rvA);
    }
  }

  // ---------- epilogue: final out[1023] (htmpf complete after last B2) ----------
  if (layer == 1) {
    float v = htmpf[(TDIM - 1) & 1][tid >> 5][tid & 31];
    out[(size_t)(bt * 16 + (tid >> 5)) * (TDIM * HDIM)
        + (size_t)(TDIM - 1) * HDIM + ct * 32 + (tid & 31)] = v;
  }
}

extern "C" void kernel_launch(void* const* d_in, const int* in_sizes, int n_in,
                              void* d_out, int out_size, void* d_ws, size_t ws_size,
                              hipStream_t stream) {
  (void)in_sizes; (void)n_in; (void)out_size; (void)ws_size;
  const float* x     = (const float*)d_in[0];
  const float* w_ih0 = (const float*)d_in[1];
  const float* w_hh0 = (const float*)d_in[2];
  const float* b0    = (const float*)d_in[3];
  const float* w_ih1 = (const float*)d_in[4];
  const float* w_hh1 = (const float*)d_in[5];
  const float* b1    = (const float*)d_in[6];
  float* out = (float*)d_out;

  char* ws = (char*)d_ws;
  uint32* h0F   = (uint32*)(ws + 0);      // [4][16]
  uint32* h1F   = (uint32*)(ws + 256);    // [4][16]
  uint32* consF = (uint32*)(ws + 512);    // [4][16]
  ushort_t* ring  = (ushort_t*)(ws + 8192);                    // [4][8][16][512] bf16 (512KB)
  ushort_t* h0buf = (ushort_t*)(ws + 8192 + 524288);           // [4][2][16][512] (128KB)
  ushort_t* h1buf = (ushort_t*)(ws + 8192 + 524288 + 131072);  // [4][2][16][512] (128KB)

  hipMemsetAsync(ws, 0, 4096, stream);
  lstm_fused<<<dim3(128), dim3(512), 0, stream>>>(
      x, w_ih0, w_hh0, b0, w_ih1, w_hh1, b1, out,
      h0F, h1F, consF, ring, h0buf, h1buf);
}

// Round 12
// 4254.196 us; speedup vs baseline: 1.0203x; 1.0203x over previous
//
#include <hip/hip_runtime.h>

#define BDIM 64
#define TDIM 1024
#define DDIM 256
#define HDIM 512
#define RING 8

typedef unsigned short ushort_t;
typedef unsigned int uint32;
typedef unsigned long long ull;
typedef __attribute__((ext_vector_type(8))) short short8;
typedef __attribute__((ext_vector_type(4))) float f32x4;

__device__ __forceinline__ ushort_t f2bf(float f) {
  union { float f; uint32 u; } v; v.f = f;
  uint32 u = v.u;
  return (ushort_t)((u + 0x7fffu + ((u >> 16) & 1u)) >> 16);
}

__device__ __forceinline__ short8 pack8(float4 a, float4 b) {
  short8 s;
  s[0] = (short)f2bf(a.x); s[1] = (short)f2bf(a.y);
  s[2] = (short)f2bf(a.z); s[3] = (short)f2bf(a.w);
  s[4] = (short)f2bf(b.x); s[5] = (short)f2bf(b.y);
  s[6] = (short)f2bf(b.z); s[7] = (short)f2bf(b.w);
  return s;
}

__device__ __forceinline__ uint32 ld_sc1(uint32* p) {
  return __hip_atomic_load(p, __ATOMIC_RELAXED, __HIP_MEMORY_SCOPE_AGENT);
}
__device__ __forceinline__ void st_sc1(uint32* p, uint32 v) {
  __hip_atomic_store(p, v, __ATOMIC_RELAXED, __HIP_MEMORY_SCOPE_AGENT);
}
__device__ __forceinline__ void st_sc1_u64(ull* p, ull v) {
  __hip_atomic_store(p, v, __ATOMIC_RELAXED, __HIP_MEMORY_SCOPE_AGENT);
}
__device__ __forceinline__ ull ld_sc1_u64(const ull* p) {
  return __hip_atomic_load((ull*)p, __ATOMIC_RELAXED, __HIP_MEMORY_SCOPE_AGENT);
}

// 16-word sc1 poll: lanes 0..15 each watch one flag; wave-wide __all join.
__device__ __forceinline__ void poll16(uint32* base, uint32 tgt, int lane, int cap) {
  int it = 0;
  for (;;) {
    uint32 v = ld_sc1(base + (lane & 15));
    if (__all((int)(v >= tgt))) break;
    __builtin_amdgcn_s_sleep(1);
    if (++it > cap) break;   // bounded: wrong beats hang
  }
  asm volatile("" ::: "memory");
}

// ---- fragment-major LDS layout (conflict-free MFMA reads, r10-proven) ----
__device__ __forceinline__ int frag_off(int row, int kf, int lg) {   // ushort units
  return kf * 512 + (((lg * 16 + row) ^ (kf & 7)) << 3);
}

// 512-thread staging of a 16x512 bf16 tile (2048 ull, row-major src) -> fragment-major
__device__ __forceinline__ void ds_stage512(ushort_t* dst, int tid, const ull* v) {
#pragma unroll
  for (int q = 0; q < 4; ++q) {
    int idx = q * 512 + tid;
    int row = idx >> 7, inner = idx & 127;
    int kf = inner >> 3, lg = (inner >> 1) & 3, e = (inner & 1) * 4;
    *(ull*)&dst[frag_off(row, kf, lg) + e] = v[q];
  }
}
__device__ __forceinline__ void load4_sc1(const ull* src, int tid, ull* v) {
#pragma unroll
  for (int q = 0; q < 4; ++q) v[q] = ld_sc1_u64(src + q * 512 + tid);
}

__global__ void __launch_bounds__(512, 1)
lstm_fused(const float* __restrict__ x,
           const float* __restrict__ w_ih0, const float* __restrict__ w_hh0,
           const float* __restrict__ b0,
           const float* __restrict__ w_ih1, const float* __restrict__ w_hh1,
           const float* __restrict__ b1,
           float* __restrict__ out,
           uint32* h0F, uint32* h1F, uint32* consF,
           ushort_t* ring, ushort_t* h0buf, ushort_t* h1buf)
{
  const int b     = (int)blockIdx.x;      // 0..127
  const int g     = b & 7;
  const int layer = g >> 2;
  const int bt    = g & 3;
  const int ct    = b >> 3;               // 0..15 (32 h-cols each)
  const int tid   = (int)threadIdx.x;
  const int wv    = tid >> 6;             // 0..7
  const int lane  = tid & 63;
  const int n     = lane & 15;            // B/C column within wave tile
  const int rg    = lane >> 4;            // C row group
  const int gsel  = n >> 2;               // gate: 0=i 1=f 2=o 3=g
  const int cgl   = n & 3;                // h-col within wave's 4

  __shared__ __align__(16) ushort_t Is[16 * 512];   // fragment-major input tile
  __shared__ __align__(16) ushort_t Hs[16 * 512];   // fragment-major h tile
  __shared__ __align__(8)  ushort_t htmpU[16][36];  // [row][col] bf16, padded (+2-way max)
  __shared__ float htmpf[2][16][32];                // layer1 deferred out

  const int NI  = layer ? 16 : 8;
  const int Din = layer ? HDIM : DDIM;
  const float* wih = layer ? w_ih1 : w_ih0;
  const float* whh = layer ? w_hh1 : w_hh0;
  const float* bb  = layer ? b1 : b0;
  const int grow = gsel * HDIM + ct * 32 + wv * 4 + cgl;

  short8 wf[32];
#pragma unroll
  for (int kf = 0; kf < 32; ++kf) wf[kf] = (short8)((short)0);
#pragma unroll
  for (int kf = 0; kf < 32; ++kf) {
    if (kf < NI + 16) {
      const float* src;
      if (kf < NI) src = wih + (size_t)grow * Din + (size_t)kf * 32 + rg * 8;
      else         src = whh + (size_t)grow * HDIM + (size_t)(kf - NI) * 32 + rg * 8;
      float4 a = *(const float4*)(src);
      float4 bq = *(const float4*)(src + 4);
      wf[kf] = pack8(a, bq);
    }
  }
  const float bias = bb[grow];
  const bool isg = (gsel == 3);

  const ull* ring_u = (const ull*)ring;                       // [4bt][8][2048]
  ull* hbuf_u = (ull*)(layer ? h1buf : h0buf) + (size_t)bt * 4096;  // [2][2048]
  uint32* hF   = (layer ? h1F : h0F) + bt * 16;               // [16]
  uint32* rF   = h0F + bt * 16;                               // ring flags = layer0 hF
  uint32* cnsF = consF + bt * 16;                             // [16]

  // x staging map (layer0): thread -> row (tid>>5), colblk (tid&31) = one chunk
  const int xrow = tid >> 5, xcb = tid & 31;

  float4 xpa, xpb;     // layer0: x[t] regs
  ull rvA[4];          // layer1: ring[t] regs
  if (layer == 0) {
    const float4* xv = (const float4*)(x + (size_t)(bt * 16 + xrow) * (TDIM * DDIM) + xcb * 8);
    xpa = xv[0]; xpb = xv[1];
  } else {
    poll16(rF, 1u, lane, 4000000);                 // ring[0] ready
    ull rv0[4];
    load4_sc1(ring_u + (size_t)bt * 16384, tid, rv0);
    ds_stage512(Is, tid, rv0);
  }

  float c4[4] = {0.f, 0.f, 0.f, 0.f};   // valid on n<4 lanes

  for (int t = 0; t < TDIM; ++t) {
    // ---- P1: polls (all waves redundantly) ----
    if (t > 0) poll16(hF, (uint32)t, lane, 200000);
    if (layer == 0 && t >= RING) poll16(cnsF, (uint32)(t - RING + 1), lane, 200000);
    // ---- P2: h[t-1] chain load ----
    ull hv[4];
    if (t > 0) load4_sc1(hbuf_u + (size_t)((t - 1) & 1) * 2048, tid, hv);
    // ---- P3: stage ----
    if (t > 0) ds_stage512(Hs, tid, hv);
    if (layer == 0) {
      *(short8*)&Is[frag_off(xrow, xcb >> 2, xcb & 3)] = pack8(xpa, xpb);
    } else if (t > 0) {
      ds_stage512(Is, tid, rvA);       // ring[t], prefetched at P8 of t-1
    }
    __syncthreads();   // B1
    // ---- post-B1: ring credit + deferred coalesced out[t-1] ----
    if (layer == 1) {
      if (tid == 0) st_sc1(cnsF + ct, (uint32)(t + 1));   // slots <= t consumed
      if (t > 0) {
        float v = htmpf[(t - 1) & 1][tid >> 5][tid & 31];
        out[(size_t)(bt * 16 + (tid >> 5)) * (TDIM * HDIM)
            + (size_t)(t - 1) * HDIM + ct * 32 + (tid & 31)] = v;
      }
    }
    // ---- P5: MFMA ----
    f32x4 acc0 = {0.f, 0.f, 0.f, 0.f}, acc1 = {0.f, 0.f, 0.f, 0.f};
#pragma unroll
    for (int kf = 0; kf < 16; ++kf) {
      if (kf < NI) {
        const short8 af = *(const short8*)&Is[frag_off(n, kf, rg)];
        if (kf & 1) acc1 = __builtin_amdgcn_mfma_f32_16x16x32_bf16(af, wf[kf], acc1, 0, 0, 0);
        else        acc0 = __builtin_amdgcn_mfma_f32_16x16x32_bf16(af, wf[kf], acc0, 0, 0, 0);
      }
    }
    if (t > 0) {
#pragma unroll
      for (int kf = 0; kf < 16; ++kf) {
        const short8 af = *(const short8*)&Hs[frag_off(n, kf, rg)];
        if (kf & 1) acc1 = __builtin_amdgcn_mfma_f32_16x16x32_bf16(af, wf[NI + kf], acc1, 0, 0, 0);
        else        acc0 = __builtin_amdgcn_mfma_f32_16x16x32_bf16(af, wf[NI + kf], acc0, 0, 0, 0);
      }
    }
    // ---- P6: activation + shfl gate exchange + pointwise (all waves) ----
    float nh4[4], nc4[4];
#pragma unroll
    for (int i = 0; i < 4; ++i) {
      float v = acc0[i] + acc1[i] + bias;
      float e = __expf(isg ? 2.f * v : -v);
      float inv = 1.f / (1.f + e);
      float act = isg ? (1.f - 2.f * inv) : inv;   // tanh for g, sigmoid else
      float fo  = __shfl_xor(act, 4, 64);
      float oo  = __shfl_xor(act, 8, 64);
      float go_ = __shfl_xor(act, 12, 64);
      float nc = fo * c4[i] + act * go_;           // valid on gsel==0 lanes
      float e2 = __expf(2.f * nc);
      float th = 1.f - 2.f / (e2 + 1.f);
      float nh = oo * th;                          // h uses UNCLIPPED c
      nc = fminf(fmaxf(nc, -50.f), 50.f);
      nh = fminf(fmaxf(nh, -50.f), 50.f);
      c4[i] = nc; nh4[i] = nh; nc4[i] = nc;
    }
    // ---- P7a: results -> LDS slab (all waves, n<4 lanes) ----
    if (n < 4) {
#pragma unroll
      for (int i = 0; i < 4; ++i) htmpU[rg * 4 + i][wv * 4 + cgl] = f2bf(nh4[i]);
      if (layer == 1) {
#pragma unroll
        for (int i = 0; i < 4; ++i) htmpf[t & 1][rg * 4 + i][wv * 4 + cgl] = nh4[i];
      }
      if (t == TDIM - 1) {
        const size_t OH = (size_t)BDIM * TDIM * HDIM;
        const size_t OC = OH + 2 * (size_t)BDIM * HDIM;
        const int hc = ct * 32 + wv * 4 + cgl;
#pragma unroll
        for (int i = 0; i < 4; ++i) {
          out[OH + (size_t)layer * BDIM * HDIM + (size_t)(bt * 16 + rg * 4 + i) * HDIM + hc] = nh4[i];
          out[OC + (size_t)layer * BDIM * HDIM + (size_t)(bt * 16 + rg * 4 + i) * HDIM + hc] = nc4[i];
        }
      }
    }
    __syncthreads();   // B2: htmpU complete
    // ---- P7b: coalesced publish (threads 0..127: 16 rows x 8 ull = 64B runs) ----
    if (tid < 128) {
      const int row = tid >> 3, k = tid & 7;
      ull hrow = *(const ull*)&htmpU[row][k * 4];
      st_sc1_u64(hbuf_u + (size_t)(t & 1) * 2048 + row * 128 + ct * 8 + k, hrow);
      if (layer == 0)
        st_sc1_u64((ull*)ring_u + (size_t)bt * 16384 + (size_t)(t & 7) * 2048
                   + row * 128 + ct * 8 + k, hrow);
    }
    asm volatile("s_waitcnt vmcnt(0)" ::: "memory");
    __syncthreads();   // B3: publish acked block-wide
    if (tid == 0) st_sc1(hF + ct, (uint32)(t + 1));    // certifies h[t] (+ring[t])
    // ---- P8: shadow prefetch for t+1 ----
    if (layer == 0) {
      if (t + 1 < TDIM) {
        const float4* xv = (const float4*)(x + (size_t)(bt * 16 + xrow) * (TDIM * DDIM)
                                             + (size_t)(t + 1) * DDIM + xcb * 8);
        xpa = xv[0]; xpb = xv[1];
      }
    } else if (t + 1 < TDIM) {
      poll16(rF, (uint32)(t + 2), lane, 200000);       // ring[t+1] certified
      load4_sc1(ring_u + (size_t)bt * 16384 + (size_t)((t + 1) & 7) * 2048, tid, rvA);
    }
  }

  // ---------- epilogue: final out[1023] ----------
  if (layer == 1) {
    float v = htmpf[(TDIM - 1) & 1][tid >> 5][tid & 31];
    out[(size_t)(bt * 16 + (tid >> 5)) * (TDIM * HDIM)
        + (size_t)(TDIM - 1) * HDIM + ct * 32 + (tid & 31)] = v;
  }
}

extern "C" void kernel_launch(void* const* d_in, const int* in_sizes, int n_in,
                              void* d_out, int out_size, void* d_ws, size_t ws_size,
                              hipStream_t stream) {
  (void)in_sizes; (void)n_in; (void)out_size; (void)ws_size;
  const float* x     = (const float*)d_in[0];
  const float* w_ih0 = (const float*)d_in[1];
  const float* w_hh0 = (const float*)d_in[2];
  const float* b0    = (const float*)d_in[3];
  const float* w_ih1 = (const float*)d_in[4];
  const float* w_hh1 = (const float*)d_in[5];
  const float* b1    = (const float*)d_in[6];
  float* out = (float*)d_out;

  char* ws = (char*)d_ws;
  uint32* h0F   = (uint32*)(ws + 0);      // [4][16]
  uint32* h1F   = (uint32*)(ws + 256);    // [4][16]
  uint32* consF = (uint32*)(ws + 512);    // [4][16]
  ushort_t* ring  = (ushort_t*)(ws + 8192);                    // [4][8][16][512] bf16 (512KB)
  ushort_t* h0buf = (ushort_t*)(ws + 8192 + 524288);           // [4][2][16][512] (128KB)
  ushort_t* h1buf = (ushort_t*)(ws + 8192 + 524288 + 131072);  // [4][2][16][512] (128KB)

  hipMemsetAsync(ws, 0, 4096, stream);
  lstm_fused<<<dim3(128), dim3(512), 0, stream>>>(
      x, w_ih0, w_hh0, b0, w_ih1, w_hh1, b1, out,
      h0F, h1F, consF, ring, h0buf, h1buf);
}